// Round 10
// baseline (133.047 us; speedup 1.0000x reference)
//
#include <hip/hip_runtime.h>
#include <hip/hip_bf16.h>
#include <hip/hip_fp16.h>

typedef _Float16 half8 __attribute__((ext_vector_type(8)));
typedef _Float16 half2v __attribute__((ext_vector_type(2)));
typedef float f32x4 __attribute__((ext_vector_type(4)));

#define B_ 4
#define C_ 64
#define O_ 64
#define H_ 128
#define W_ 128
#define HT 8     // tile rows
#define WT 16    // tile cols
#define HALO 3
#define RS 14    // staged rows (HT + 2*HALO)
#define CS 22    // staged cols (WT + 2*HALO)
// xs layout: [pixel][ch], pixel stride 72 f16 = 144B = 9 half8/uint4 slots

__device__ __forceinline__ unsigned pkh(float lo, float hi) {
  half2v v = {(_Float16)lo, (_Float16)hi};
  return __builtin_bit_cast(unsigned, v);
}

// ---------------------------------------------------------------------------
// Kernel 0: pre-build fragment-ready f16 weights in workspace.
//  wf  (deform_w): 18 k-steps x 4 o-tiles x 64 lanes x 8 = 36864 f16
//  wfm (mask_w padded to 16 rows): 18 k-steps x 64 lanes x 8 = 9216 f16
// ---------------------------------------------------------------------------
__global__ void build_frags(const float* __restrict__ dw,
                            const float* __restrict__ mw,
                            _Float16* __restrict__ wsb) {
  int t = blockIdx.x * 256 + threadIdx.x;
  if (t < 36864) {
    int j = t & 7, lane = (t >> 3) & 63, ot = (t >> 9) & 3, s = t >> 11;
    int kk = s >> 1, ch = s & 1;
    int o = ot * 16 + (lane & 15);
    int c = ch * 32 + ((lane >> 4) << 3) + j;
    wsb[t] = (_Float16)dw[(o * 64 + c) * 9 + kk];
  } else if (t < 46080) {
    int t2 = t - 36864;
    int j = t2 & 7, lane = (t2 >> 3) & 63, s = t2 >> 9;
    int km = lane & 15;
    int c = (s & 1) * 32 + ((lane >> 4) << 3) + j;
    int tap = s >> 1;
    float v = (km < 9) ? mw[(km * 64 + c) * 9 + tap] : 0.0f;
    wsb[t] = (_Float16)v;
  }
}

// ---------------------------------------------------------------------------
// Main fused kernel. 512 blocks x 512 threads (8 waves; wave = pixel row).
// LDS: 44352 (xs) + 4608 (offl) + 2304 (maskl) + 9216 (cwb) + 4608 (crc)
//    = 65088 B <= 65536.  2 blocks/CU -> 4 waves/SIMD -> VGPR budget 512.
// Deform weights preloaded to a 72-entry register array (288 VGPR).
// ---------------------------------------------------------------------------
__global__ __launch_bounds__(512, 4)
void deform_main(const float* __restrict__ x,
                 const float* __restrict__ ele,
                 const float* __restrict__ ow,
                 const float* __restrict__ ob,
                 const float* __restrict__ mb,
                 const _Float16* __restrict__ wsb,
                 float* __restrict__ out) {
  __shared__ uint4 xs4[RS * CS * 9];       // 44352 B, f16 data
  __shared__ _Float16 offl[128 * 18];      //  4608 B
  __shared__ _Float16 maskl[128 * 9];      //  2304 B
  __shared__ uint2 cwb[128 * 9];           //  9216 B  packed (a00,a01),(a10,a11)
  __shared__ unsigned crc[128 * 9];        //  4608 B  rc00 | drow<<16 | dcol<<24

  const int tid = threadIdx.x;
  const int lane = tid & 63;
  const int wv = tid >> 6;        // 0..7 = pixel row within tile
  const int pcl = lane & 15;      // pixel col within tile / MFMA col
  const int lq = lane >> 4;       // k-slice quadrant

  // XCD-bijective swizzle: consecutive decoded tiles land on the same XCD.
  const int bid = blockIdx.x;
  const int d = ((bid & 7) << 6) + (bid >> 3);   // 512 % 8 == 0 -> bijective
  const int b = d >> 7;
  const int t7 = d & 127;
  const int r0 = (t7 >> 3) * HT;   // 16 row-tiles
  const int c0 = (t7 & 7) * WT;    // 8 col-tiles

  // ---- Early: issue phase-2 ele loads (latency hidden under staging) -----
  float ev[9];
  {
    int tl = tid & 127;
    int pr = tl >> 4, pc = tl & 15;
    int h = r0 + pr, w = c0 + pc;
#pragma unroll
    for (int ty = 0; ty < 3; ++ty)
#pragma unroll
      for (int tx = 0; tx < 3; ++tx) {
        int gy = h - 1 + ty, gx = w - 1 + tx;
        float v = 0.0f;
        if ((unsigned)gy < 128u && (unsigned)gx < 128u)
          v = ele[b * (H_ * W_) + (gy << 7) + gx];
        ev[ty * 3 + tx] = v;
      }
  }

  // ---- Phase 1: stage x patch to LDS as f16, packed-pair writes ----------
  {
    _Float16* xsb = (_Float16*)xs4;
    const int c2 = tid >> 4;               // 0..31
    const int pl = tid & 15;
    const float* xb0 = x + b * (C_ * H_ * W_) + (2 * c2) * (H_ * W_);
    const float* xb1 = xb0 + (H_ * W_);
    for (int p = pl; p < RS * CS; p += 16) {
      int row = (p * 2979) >> 16;          // p / 22 for p < 700
      int col = p - row * CS;
      int gy = r0 - HALO + row, gx = c0 - HALO + col;
      float v0 = 0.0f, v1 = 0.0f;
      if ((unsigned)gy < 128u && (unsigned)gx < 128u) {
        int gi = (gy << 7) + gx;
        v0 = xb0[gi];
        v1 = xb1[gi];
      }
      half2v hv = {(_Float16)v0, (_Float16)v1};
      *(half2v*)&xsb[p * 72 + 2 * c2] = hv;
    }
  }

  // ---- Preload all 72 deform-weight fragments into registers -------------
  // 72 x half8 = 288 VGPR; statically indexed everywhere (rule #20).
  const half8* wf8 = (const half8*)wsb;
  half8 wreg[72];
#pragma unroll
  for (int i = 0; i < 72; ++i) wreg[i] = wf8[i * 64 + lane];

  // ---- Phase 2: offset conv (1->18ch 3x3), threads < 128, one px each ----
  if (tid < 128) {
#pragma unroll
    for (int ci = 0; ci < 18; ++ci) {
      float a = ob[ci];
#pragma unroll
      for (int tap = 0; tap < 9; ++tap) a += ev[tap] * ow[ci * 9 + tap];
      offl[tid * 18 + ci] = (_Float16)a;
    }
  }
  __syncthreads();   // xs + offl ready

  // ---- Phase 3: mask conv (64->9ch 3x3 + sigmoid) via f16 MFMA -----------
  {
    const half8* wfm8 = ((const half8*)wsb) + 4608;  // after 36864 f16
    f32x4 macc = {0.f, 0.f, 0.f, 0.f};
#pragma unroll
    for (int s = 0; s < 18; ++s) {
      const int tap = s >> 1;
      const int chalf = s & 1;
      const int ty = tap / 3, tx = tap - ty * 3;
      half8 aw = wfm8[s * 64 + lane];
      const int csl = chalf * 4 + lq;
      int rc = (wv + (HALO - 1) + ty) * CS + (pcl + (HALO - 1) + tx);
      half8 xv = *(const half8*)(xs4 + rc * 9 + csl);
      macc = __builtin_amdgcn_mfma_f32_16x16x32_f16(aw, xv, macc, 0, 0, 0);
    }
    int px = wv * 16 + pcl;
#pragma unroll
    for (int r = 0; r < 4; ++r) {
      int km = lq * 4 + r;
      if (km < 9) {
        float a = macc[r] + mb[km];
        float m = 1.0f / (1.0f + __expf(-a));
        maskl[px * 9 + km] = (_Float16)m;
      }
    }
  }
  __syncthreads();   // maskl ready

  // ---- Phase 2b: bilinear coefficient precompute (all 512 threads) -------
  for (int it = tid; it < 128 * 9; it += 512) {
    int px = (it * 7282) >> 16;            // it / 9 for it < 1152
    int kk = it - px * 9;
    int pr = px >> 4, pc = px & 15;
    int h = r0 + pr, w = c0 + pc;
    int ky = kk / 3 - 1;
    int kx = kk - (kk / 3) * 3 - 1;
    half2v o2 = *(const half2v*)&offl[px * 18 + kk * 2];
    float m = (float)maskl[px * 9 + kk];
    float py = (float)(h + ky) + (float)o2[0];
    float pxx = (float)(w + kx) + (float)o2[1];
    float fy = floorf(py), fx = floorf(pxx);
    float wy = py - fy, wx = pxx - fx;
    int iy = (int)fy - r0 + HALO;
    int ix = (int)fx - c0 + HALO;
    int vy0 = (unsigned)iy < (unsigned)RS;
    int vy1 = (unsigned)(iy + 1) < (unsigned)RS;
    int vx0 = (unsigned)ix < (unsigned)CS;
    int vx1 = (unsigned)(ix + 1) < (unsigned)CS;
    int cy0 = min(max(iy, 0), RS - 1), cy1 = min(max(iy + 1, 0), RS - 1);
    int cx0 = min(max(ix, 0), CS - 1), cx1 = min(max(ix + 1, 0), CS - 1);
    float wy0 = 1.0f - wy, wx0 = 1.0f - wx;
    float a00 = wy0 * wx0 * m * (float)(vy0 & vx0);
    float a01 = wy0 * wx * m * (float)(vy0 & vx1);
    float a10 = wy * wx0 * m * (float)(vy1 & vx0);
    float a11 = wy * wx * m * (float)(vy1 & vx1);
    int rc00 = cy0 * CS + cx0;
    int drow = (cy1 - cy0) * CS;           // 0 or 22
    int dcol = cx1 - cx0;                  // 0 or 1
    uint2 cv;
    cv.x = pkh(a00, a01);
    cv.y = pkh(a10, a11);
    cwb[it] = cv;
    crc[it] = (unsigned)rc00 | ((unsigned)drow << 16) | ((unsigned)dcol << 24);
  }
  __syncthreads();   // coefficients ready

  // ---- Phase 4: streaming gather-blend + MFMA (weights in registers) -----
  f32x4 acc[4];
#pragma unroll
  for (int ot = 0; ot < 4; ++ot) {
    f32x4 z = {0.f, 0.f, 0.f, 0.f};
    acc[ot] = z;
  }

  const int px = wv * 16 + pcl;

#pragma unroll
  for (int kk = 0; kk < 9; ++kk) {
    uint2 cv = cwb[px * 9 + kk];
    unsigned rv = crc[px * 9 + kk];
    int rc00 = rv & 0xFFFF;
    int drow = (rv >> 16) & 0xFF;
    int dcol = rv >> 24;
    int rc01 = rc00 + dcol;
    int rc10 = rc00 + drow;
    int rc11 = rc10 + dcol;
    half2v c01 = __builtin_bit_cast(half2v, cv.x);
    half2v c23 = __builtin_bit_cast(half2v, cv.y);
    _Float16 a00 = c01[0], a01 = c01[1], a10 = c23[0], a11 = c23[1];
    half8 a00s = {a00, a00, a00, a00, a00, a00, a00, a00};
    half8 a01s = {a01, a01, a01, a01, a01, a01, a01, a01};
    half8 a10s = {a10, a10, a10, a10, a10, a10, a10, a10};
    half8 a11s = {a11, a11, a11, a11, a11, a11, a11, a11};
#pragma unroll
    for (int ch = 0; ch < 2; ++ch) {
      const int csl = ch * 4 + lq;
      half8 v00 = *(const half8*)(xs4 + rc00 * 9 + csl);
      half8 v01 = *(const half8*)(xs4 + rc01 * 9 + csl);
      half8 v10 = *(const half8*)(xs4 + rc10 * 9 + csl);
      half8 v11 = *(const half8*)(xs4 + rc11 * 9 + csl);
      half8 t = v00 * a00s + v01 * a01s + v10 * a10s + v11 * a11s;
      const int sidx = kk * 2 + ch;
#pragma unroll
      for (int ot = 0; ot < 4; ++ot)
        acc[ot] = __builtin_amdgcn_mfma_f32_16x16x32_f16(wreg[sidx * 4 + ot], t,
                                                         acc[ot], 0, 0, 0);
    }
  }

  // ---- Epilogue: ReLU -> fp32 -> global ----
  const int h = r0 + wv;
  const int w = c0 + pcl;
#pragma unroll
  for (int ot = 0; ot < 4; ++ot) {
#pragma unroll
    for (int r = 0; r < 4; ++r) {
      int o = ot * 16 + lq * 4 + r;
      float v = fmaxf(acc[ot][r], 0.0f);
      out[((b * O_ + o) << 14) + (h << 7) + w] = v;
    }
  }
}

extern "C" void kernel_launch(void* const* d_in, const int* in_sizes, int n_in,
                              void* d_out, int out_size, void* d_ws, size_t ws_size,
                              hipStream_t stream) {
  const float* x   = (const float*)d_in[0];
  const float* ele = (const float*)d_in[1];
  const float* ow  = (const float*)d_in[2];
  const float* ob  = (const float*)d_in[3];
  const float* mw  = (const float*)d_in[4];
  const float* mb  = (const float*)d_in[5];
  const float* dw  = (const float*)d_in[6];
  _Float16* wsb = (_Float16*)d_ws;

  build_frags<<<180, 256, 0, stream>>>(dw, mw, wsb);
  deform_main<<<512, 512, 0, stream>>>(x, ele, ow, ob, mb, wsb,
                                       (float*)d_out);
}

// Round 11
// 38.847 us; speedup vs baseline: 3.4249x; 3.4249x over previous
//
#include <hip/hip_runtime.h>
#include <hip/hip_bf16.h>
#include <hip/hip_fp16.h>

typedef _Float16 half8 __attribute__((ext_vector_type(8)));
typedef _Float16 half2v __attribute__((ext_vector_type(2)));
typedef float f32x4 __attribute__((ext_vector_type(4)));

#define B_ 4
#define C_ 64
#define O_ 64
#define H_ 128
#define W_ 128
#define HT 8     // tile rows
#define WT 8     // tile cols
#define HALO 3
#define RS 14    // staged rows (HT + 2*HALO)
#define CS 14    // staged cols (WT + 2*HALO)
// xs layout: [pixel][ch], pixel stride 72 f16 = 144B = 9 half8/uint4 slots

__device__ __forceinline__ unsigned pkh(float lo, float hi) {
  half2v v = {(_Float16)lo, (_Float16)hi};
  return __builtin_bit_cast(unsigned, v);
}

// ---------------------------------------------------------------------------
// Kernel 0: pre-build fragment-ready f16 weights in workspace.
//  wf  (deform_w): 18 k-steps x 4 o-tiles x 64 lanes x 8 = 36864 f16
//  wfm (mask_w padded to 16 rows): 18 k-steps x 64 lanes x 8 = 9216 f16
// ---------------------------------------------------------------------------
__global__ void build_frags(const float* __restrict__ dw,
                            const float* __restrict__ mw,
                            _Float16* __restrict__ wsb) {
  int t = blockIdx.x * 256 + threadIdx.x;
  if (t < 36864) {
    int j = t & 7, lane = (t >> 3) & 63, ot = (t >> 9) & 3, s = t >> 11;
    int kk = s >> 1, ch = s & 1;
    int o = ot * 16 + (lane & 15);
    int c = ch * 32 + ((lane >> 4) << 3) + j;
    wsb[t] = (_Float16)dw[(o * 64 + c) * 9 + kk];
  } else if (t < 46080) {
    int t2 = t - 36864;
    int j = t2 & 7, lane = (t2 >> 3) & 63, s = t2 >> 9;
    int km = lane & 15;
    int c = (s & 1) * 32 + ((lane >> 4) << 3) + j;
    int tap = s >> 1;
    float v = (km < 9) ? mw[(km * 64 + c) * 9 + tap] : 0.0f;
    wsb[t] = (_Float16)v;
  }
}

// ---------------------------------------------------------------------------
// Main fused kernel. 1024 blocks x 256 threads (4 waves; wave wv owns the
// 16 pixels px = wv*16 + pcl of an 8x8 tile).
// LDS: 28224 (xs) + 2304 (offl) + 1152 (maskl) + 4608 (cwb) + 2304 (crc)
//    = 38592 B -> 4 blocks/CU (154.4 KB of 160 KB pool), 16 waves/CU.
// ---------------------------------------------------------------------------
__global__ __launch_bounds__(256, 4)
void deform_main(const float* __restrict__ x,
                 const float* __restrict__ ele,
                 const float* __restrict__ ow,
                 const float* __restrict__ ob,
                 const float* __restrict__ mb,
                 const _Float16* __restrict__ wsb,
                 float* __restrict__ out) {
  __shared__ uint4 xs4[RS * CS * 9];       // 28224 B, f16 data
  __shared__ _Float16 offl[64 * 18];       //  2304 B
  __shared__ _Float16 maskl[64 * 9];       //  1152 B
  __shared__ uint2 cwb[64 * 9];            //  4608 B  packed (a00,a01),(a10,a11)
  __shared__ unsigned crc[64 * 9];         //  2304 B  rc00 | drow<<16 | dcol<<24

  const int tid = threadIdx.x;
  const int lane = tid & 63;
  const int wv = tid >> 6;        // 0..3
  const int pcl = lane & 15;      // MFMA col -> pixel px = wv*16+pcl
  const int lq = lane >> 4;       // k-slice quadrant

  // XCD-bijective swizzle (1024 % 8 == 0): 128 consecutive tiles per XCD.
  const int bid = blockIdx.x;
  const int d = ((bid & 7) << 7) + (bid >> 3);
  const int b = d >> 8;
  const int t8 = d & 255;
  const int r0 = (t8 >> 4) * HT;   // 16 row-tiles
  const int c0 = (t8 & 15) * WT;   // 16 col-tiles

  // ---- Early: issue offset-conv ele loads (px = tid>>2, 4x shared) -------
  float ev[9];
  {
    int px = tid >> 2;
    int pr = px >> 3, pc = px & 7;
    int h = r0 + pr, w = c0 + pc;
#pragma unroll
    for (int ty = 0; ty < 3; ++ty)
#pragma unroll
      for (int tx = 0; tx < 3; ++tx) {
        int gy = h - 1 + ty, gx = w - 1 + tx;
        float v = 0.0f;
        if ((unsigned)gy < 128u && (unsigned)gx < 128u)
          v = ele[b * (H_ * W_) + (gy << 7) + gx];
        ev[ty * 3 + tx] = v;
      }
  }

  // ---- Phase 1: stage x patch (14x14 halo) to LDS as f16 -----------------
  // thread t owns channels {2*(t>>3), 2*(t>>3)+1}, pixels (t&7)+8k.
  {
    _Float16* xsb = (_Float16*)xs4;
    const int c2 = tid >> 3;               // 0..31 channel-pair
    const int pl = tid & 7;
    const float* xb0 = x + b * (C_ * H_ * W_) + (2 * c2) * (H_ * W_);
    const float* xb1 = xb0 + (H_ * W_);
    for (int p = pl; p < RS * CS; p += 8) {
      int row = (p * 4682) >> 16;          // p / 14 for p < 900
      int col = p - row * CS;
      int gy = r0 - HALO + row, gx = c0 - HALO + col;
      float v0 = 0.0f, v1 = 0.0f;
      if ((unsigned)gy < 128u && (unsigned)gx < 128u) {
        int gi = (gy << 7) + gx;
        v0 = xb0[gi];
        v1 = xb1[gi];
      }
      half2v hv = {(_Float16)v0, (_Float16)v1};
      *(half2v*)&xsb[p * 72 + 2 * c2] = hv;
    }
  }

  // ---- Phase 2: offset conv (1->18ch 3x3); px = tid>>2, ci = (tid&3)+4k --
  {
    int px = tid >> 2;
    int g = tid & 3;
#pragma unroll
    for (int k5 = 0; k5 < 5; ++k5) {
      int ci = g + k5 * 4;
      if (ci < 18) {
        float a = ob[ci];
#pragma unroll
        for (int tap = 0; tap < 9; ++tap) a += ev[tap] * ow[ci * 9 + tap];
        offl[px * 18 + ci] = (_Float16)a;
      }
    }
  }
  __syncthreads();   // xs + offl ready

  // ---- Phase 3: mask conv (64->9ch 3x3 + sigmoid) via f16 MFMA -----------
  {
    const half8* wfm8 = ((const half8*)wsb) + 4608;  // after 36864 f16
    f32x4 macc = {0.f, 0.f, 0.f, 0.f};
    const int px = wv * 16 + pcl;
    const int pr = px >> 3, pc = px & 7;
#pragma unroll
    for (int s = 0; s < 18; ++s) {
      const int tap = s >> 1;
      const int chalf = s & 1;
      const int ty = tap / 3, tx = tap - ty * 3;
      half8 aw = wfm8[s * 64 + lane];
      const int csl = chalf * 4 + lq;
      int rc = (pr + (HALO - 1) + ty) * CS + (pc + (HALO - 1) + tx);
      half8 xv = *(const half8*)(xs4 + rc * 9 + csl);
      macc = __builtin_amdgcn_mfma_f32_16x16x32_f16(aw, xv, macc, 0, 0, 0);
    }
#pragma unroll
    for (int r = 0; r < 4; ++r) {
      int km = lq * 4 + r;
      if (km < 9) {
        float a = macc[r] + mb[km];
        float m = 1.0f / (1.0f + __expf(-a));
        maskl[px * 9 + km] = (_Float16)m;
      }
    }
  }
  __syncthreads();   // maskl ready

  // ---- Phase 2b: bilinear coefficient precompute (all 256 threads) -------
  for (int it = tid; it < 64 * 9; it += 256) {
    int px = (it * 7282) >> 16;            // it / 9 for it < 1152
    int kk = it - px * 9;
    int pr = px >> 3, pc = px & 7;
    int h = r0 + pr, w = c0 + pc;
    int ky = kk / 3 - 1;
    int kx = kk - (kk / 3) * 3 - 1;
    half2v o2 = *(const half2v*)&offl[px * 18 + kk * 2];
    float m = (float)maskl[px * 9 + kk];
    float py = (float)(h + ky) + (float)o2[0];
    float pxx = (float)(w + kx) + (float)o2[1];
    float fy = floorf(py), fx = floorf(pxx);
    float wy = py - fy, wx = pxx - fx;
    int iy = (int)fy - r0 + HALO;
    int ix = (int)fx - c0 + HALO;
    int vy0 = (unsigned)iy < (unsigned)RS;
    int vy1 = (unsigned)(iy + 1) < (unsigned)RS;
    int vx0 = (unsigned)ix < (unsigned)CS;
    int vx1 = (unsigned)(ix + 1) < (unsigned)CS;
    int cy0 = min(max(iy, 0), RS - 1), cy1 = min(max(iy + 1, 0), RS - 1);
    int cx0 = min(max(ix, 0), CS - 1), cx1 = min(max(ix + 1, 0), CS - 1);
    float wy0 = 1.0f - wy, wx0 = 1.0f - wx;
    float a00 = wy0 * wx0 * m * (float)(vy0 & vx0);
    float a01 = wy0 * wx * m * (float)(vy0 & vx1);
    float a10 = wy * wx0 * m * (float)(vy1 & vx0);
    float a11 = wy * wx * m * (float)(vy1 & vx1);
    int rc00 = cy0 * CS + cx0;
    int drow = (cy1 - cy0) * CS;           // 0 or 14
    int dcol = cx1 - cx0;                  // 0 or 1
    uint2 cv;
    cv.x = pkh(a00, a01);
    cv.y = pkh(a10, a11);
    cwb[it] = cv;
    crc[it] = (unsigned)rc00 | ((unsigned)drow << 16) | ((unsigned)dcol << 24);
  }
  __syncthreads();   // coefficients ready

  // ---- Phase 4: streaming gather-blend + MFMA ----------------------------
  const half8* wf8 = (const half8*)wsb;
  f32x4 acc[4];
#pragma unroll
  for (int ot = 0; ot < 4; ++ot) {
    f32x4 z = {0.f, 0.f, 0.f, 0.f};
    acc[ot] = z;
  }

  const int px = wv * 16 + pcl;

#pragma unroll
  for (int kk = 0; kk < 9; ++kk) {
    uint2 cv = cwb[px * 9 + kk];
    unsigned rv = crc[px * 9 + kk];
    int rc00 = rv & 0xFFFF;
    int drow = (rv >> 16) & 0xFF;
    int dcol = rv >> 24;
    int rc01 = rc00 + dcol;
    int rc10 = rc00 + drow;
    int rc11 = rc10 + dcol;
    half2v c01 = __builtin_bit_cast(half2v, cv.x);
    half2v c23 = __builtin_bit_cast(half2v, cv.y);
    _Float16 a00 = c01[0], a01 = c01[1], a10 = c23[0], a11 = c23[1];
    half8 a00s = {a00, a00, a00, a00, a00, a00, a00, a00};
    half8 a01s = {a01, a01, a01, a01, a01, a01, a01, a01};
    half8 a10s = {a10, a10, a10, a10, a10, a10, a10, a10};
    half8 a11s = {a11, a11, a11, a11, a11, a11, a11, a11};
#pragma unroll
    for (int ch = 0; ch < 2; ++ch) {
      const int csl = ch * 4 + lq;
      half8 v00 = *(const half8*)(xs4 + rc00 * 9 + csl);
      half8 v01 = *(const half8*)(xs4 + rc01 * 9 + csl);
      half8 v10 = *(const half8*)(xs4 + rc10 * 9 + csl);
      half8 v11 = *(const half8*)(xs4 + rc11 * 9 + csl);
      half8 t = v00 * a00s + v01 * a01s + v10 * a10s + v11 * a11s;
      const int sidx = kk * 2 + ch;
#pragma unroll
      for (int ot = 0; ot < 4; ++ot) {
        half8 bw = wf8[(sidx * 4 + ot) * 64 + lane];
        acc[ot] = __builtin_amdgcn_mfma_f32_16x16x32_f16(bw, t, acc[ot], 0, 0, 0);
      }
    }
  }

  // ---- Epilogue: ReLU -> fp32 -> global ----
  const int pr = px >> 3, pc = px & 7;
  const int h = r0 + pr;
  const int w = c0 + pc;
#pragma unroll
  for (int ot = 0; ot < 4; ++ot) {
#pragma unroll
    for (int r = 0; r < 4; ++r) {
      int o = ot * 16 + lq * 4 + r;
      float v = fmaxf(acc[ot][r], 0.0f);
      out[((b * O_ + o) << 14) + (h << 7) + w] = v;
    }
  }
}

extern "C" void kernel_launch(void* const* d_in, const int* in_sizes, int n_in,
                              void* d_out, int out_size, void* d_ws, size_t ws_size,
                              hipStream_t stream) {
  const float* x   = (const float*)d_in[0];
  const float* ele = (const float*)d_in[1];
  const float* ow  = (const float*)d_in[2];
  const float* ob  = (const float*)d_in[3];
  const float* mw  = (const float*)d_in[4];
  const float* mb  = (const float*)d_in[5];
  const float* dw  = (const float*)d_in[6];
  _Float16* wsb = (_Float16*)d_ws;

  build_frags<<<180, 256, 0, stream>>>(dw, mw, wsb);
  deform_main<<<1024, 256, 0, stream>>>(x, ele, ow, ob, mb, wsb,
                                        (float*)d_out);
}

// Round 12
// 32.171 us; speedup vs baseline: 4.1356x; 1.2075x over previous
//
#include <hip/hip_runtime.h>
#include <hip/hip_bf16.h>
#include <hip/hip_fp16.h>

typedef _Float16 half8 __attribute__((ext_vector_type(8)));
typedef _Float16 half2v __attribute__((ext_vector_type(2)));
typedef float f32x4 __attribute__((ext_vector_type(4)));

#define B_ 4
#define C_ 64
#define O_ 64
#define H_ 128
#define W_ 128
#define HT 8     // tile rows
#define WT 16    // tile cols
#define HALO 3
#define RS 14    // staged rows (HT + 2*HALO)
#define CS 22    // staged cols (WT + 2*HALO)
// xs layout: [pixel][ch], pixel stride 72 f16 = 144B = 9 half8/uint4 slots

__device__ __forceinline__ unsigned pkh(float lo, float hi) {
  half2v v = {(_Float16)lo, (_Float16)hi};
  return __builtin_bit_cast(unsigned, v);
}

// ---------------------------------------------------------------------------
// Kernel 0: pre-build fragment-ready f16 weights in workspace.
//  wf  (deform_w): 18 k-steps x 4 o-tiles x 64 lanes x 8 = 36864 f16
//  wfm (mask_w padded to 16 rows): 18 k-steps x 64 lanes x 8 = 9216 f16
// ---------------------------------------------------------------------------
__global__ void build_frags(const float* __restrict__ dw,
                            const float* __restrict__ mw,
                            _Float16* __restrict__ wsb) {
  int t = blockIdx.x * 256 + threadIdx.x;
  if (t < 36864) {
    int j = t & 7, lane = (t >> 3) & 63, ot = (t >> 9) & 3, s = t >> 11;
    int kk = s >> 1, ch = s & 1;
    int o = ot * 16 + (lane & 15);
    int c = ch * 32 + ((lane >> 4) << 3) + j;
    wsb[t] = (_Float16)dw[(o * 64 + c) * 9 + kk];
  } else if (t < 46080) {
    int t2 = t - 36864;
    int j = t2 & 7, lane = (t2 >> 3) & 63, s = t2 >> 9;
    int km = lane & 15;
    int c = (s & 1) * 32 + ((lane >> 4) << 3) + j;
    int tap = s >> 1;
    float v = (km < 9) ? mw[(km * 64 + c) * 9 + tap] : 0.0f;
    wsb[t] = (_Float16)v;
  }
}

// ---------------------------------------------------------------------------
// Main fused kernel. 512 blocks x 512 threads (8 waves; wave = pixel row).
// LDS: 44352 (xs) + 4608 (offl) + 9216 (cwb) + 4608 (crc) = 62784 B
// Two barriers total (coef compute fused into phase-3 MFMA epilogue).
// ---------------------------------------------------------------------------
__global__ __launch_bounds__(512, 4)
void deform_main(const float* __restrict__ x,
                 const float* __restrict__ ele,
                 const float* __restrict__ ow,
                 const float* __restrict__ ob,
                 const float* __restrict__ mb,
                 const _Float16* __restrict__ wsb,
                 float* __restrict__ out) {
  __shared__ uint4 xs4[RS * CS * 9];       // 44352 B, f16 data
  __shared__ _Float16 offl[128 * 18];      //  4608 B
  __shared__ uint2 cwb[128 * 9];           //  9216 B  packed (a00,a01),(a10,a11)
  __shared__ unsigned crc[128 * 9];        //  4608 B  rc00 | drow<<16 | dcol<<24

  const int tid = threadIdx.x;
  const int lane = tid & 63;
  const int wv = tid >> 6;        // 0..7 = pixel row within tile
  const int pcl = lane & 15;      // pixel col within tile / MFMA col
  const int lq = lane >> 4;       // k-slice quadrant

  // XCD-bijective swizzle: consecutive decoded tiles land on the same XCD.
  const int bid = blockIdx.x;
  const int d = ((bid & 7) << 6) + (bid >> 3);   // 512 % 8 == 0 -> bijective
  const int b = d >> 7;
  const int t7 = d & 127;
  const int r0 = (t7 >> 3) * HT;   // 16 row-tiles
  const int c0 = (t7 & 7) * WT;    // 8 col-tiles

  // ---- Early: issue phase-2 ele loads (latency hidden under staging) -----
  float ev[9];
  {
    int tl = tid & 127;
    int pr = tl >> 4, pc = tl & 15;
    int h = r0 + pr, w = c0 + pc;
#pragma unroll
    for (int ty = 0; ty < 3; ++ty)
#pragma unroll
      for (int tx = 0; tx < 3; ++tx) {
        int gy = h - 1 + ty, gx = w - 1 + tx;
        float v = 0.0f;
        if ((unsigned)gy < 128u && (unsigned)gx < 128u)
          v = ele[b * (H_ * W_) + (gy << 7) + gx];
        ev[ty * 3 + tx] = v;
      }
  }

  // ---- Phase 1: stage x patch to LDS as f16, packed-pair writes ----------
  {
    _Float16* xsb = (_Float16*)xs4;
    const int c2 = tid >> 4;               // 0..31
    const int pl = tid & 15;
    const float* xb0 = x + b * (C_ * H_ * W_) + (2 * c2) * (H_ * W_);
    const float* xb1 = xb0 + (H_ * W_);
    for (int p = pl; p < RS * CS; p += 16) {
      int row = (p * 2979) >> 16;          // p / 22 for p < 700
      int col = p - row * CS;
      int gy = r0 - HALO + row, gx = c0 - HALO + col;
      float v0 = 0.0f, v1 = 0.0f;
      if ((unsigned)gy < 128u && (unsigned)gx < 128u) {
        int gi = (gy << 7) + gx;
        v0 = xb0[gi];
        v1 = xb1[gi];
      }
      half2v hv = {(_Float16)v0, (_Float16)v1};
      *(half2v*)&xsb[p * 72 + 2 * c2] = hv;
    }
  }

  // ---- Phase 2: offset conv (1->18ch 3x3), threads < 128, one px each ----
  if (tid < 128) {
#pragma unroll
    for (int ci = 0; ci < 18; ++ci) {
      float a = ob[ci];
#pragma unroll
      for (int tap = 0; tap < 9; ++tap) a += ev[tap] * ow[ci * 9 + tap];
      offl[tid * 18 + ci] = (_Float16)a;
    }
  }
  __syncthreads();   // xs + offl ready

  // ---- Phase 3: mask conv via f16 MFMA + FUSED sigmoid+coef epilogue -----
  {
    const half8* wfm8 = ((const half8*)wsb) + 4608;  // after 36864 f16
    f32x4 macc = {0.f, 0.f, 0.f, 0.f};
#pragma unroll
    for (int s = 0; s < 18; ++s) {
      const int tap = s >> 1;
      const int chalf = s & 1;
      const int ty = tap / 3, tx = tap - ty * 3;
      half8 aw = wfm8[s * 64 + lane];
      const int csl = chalf * 4 + lq;
      int rc = (wv + (HALO - 1) + ty) * CS + (pcl + (HALO - 1) + tx);
      half8 xv = *(const half8*)(xs4 + rc * 9 + csl);
      macc = __builtin_amdgcn_mfma_f32_16x16x32_f16(aw, xv, macc, 0, 0, 0);
    }
    // Fused epilogue: this lane owns (px, kk = lq*4 + r), exact cover of 0..8.
    const int px = wv * 16 + pcl;
    const int h = r0 + wv, w = c0 + pcl;
#pragma unroll
    for (int r = 0; r < 4; ++r) {
      int kk = lq * 4 + r;
      if (kk < 9) {
        float a = macc[r] + mb[kk];
        float m = 1.0f / (1.0f + __expf(-a));
        int ky = kk / 3 - 1;
        int kx = kk - (kk / 3) * 3 - 1;
        half2v o2 = *(const half2v*)&offl[px * 18 + kk * 2];
        float py = (float)(h + ky) + (float)o2[0];
        float pxx = (float)(w + kx) + (float)o2[1];
        float fy = floorf(py), fx = floorf(pxx);
        float wy = py - fy, wx = pxx - fx;
        int iy = (int)fy - r0 + HALO;
        int ix = (int)fx - c0 + HALO;
        int vy0 = (unsigned)iy < (unsigned)RS;
        int vy1 = (unsigned)(iy + 1) < (unsigned)RS;
        int vx0 = (unsigned)ix < (unsigned)CS;
        int vx1 = (unsigned)(ix + 1) < (unsigned)CS;
        int cy0 = min(max(iy, 0), RS - 1), cy1 = min(max(iy + 1, 0), RS - 1);
        int cx0 = min(max(ix, 0), CS - 1), cx1 = min(max(ix + 1, 0), CS - 1);
        float wy0 = 1.0f - wy, wx0 = 1.0f - wx;
        float a00 = wy0 * wx0 * m * (float)(vy0 & vx0);
        float a01 = wy0 * wx * m * (float)(vy0 & vx1);
        float a10 = wy * wx0 * m * (float)(vy1 & vx0);
        float a11 = wy * wx * m * (float)(vy1 & vx1);
        int rc00 = cy0 * CS + cx0;
        int drow = (cy1 - cy0) * CS;           // 0 or 22
        int dcol = cx1 - cx0;                  // 0 or 1
        uint2 cv;
        cv.x = pkh(a00, a01);
        cv.y = pkh(a10, a11);
        cwb[px * 9 + kk] = cv;
        crc[px * 9 + kk] =
            (unsigned)rc00 | ((unsigned)drow << 16) | ((unsigned)dcol << 24);
      }
    }
  }
  __syncthreads();   // coefficients ready

  // ---- Phase 4: streaming gather-blend + MFMA ----------------------------
  const half8* wf8 = (const half8*)wsb;
  f32x4 acc[4];
#pragma unroll
  for (int ot = 0; ot < 4; ++ot) {
    f32x4 z = {0.f, 0.f, 0.f, 0.f};
    acc[ot] = z;
  }

  const int px = wv * 16 + pcl;

#pragma unroll
  for (int kk = 0; kk < 9; ++kk) {
    uint2 cv = cwb[px * 9 + kk];
    unsigned rv = crc[px * 9 + kk];
    int rc00 = rv & 0xFFFF;
    int drow = (rv >> 16) & 0xFF;
    int dcol = rv >> 24;
    int rc01 = rc00 + dcol;
    int rc10 = rc00 + drow;
    int rc11 = rc10 + dcol;
    half2v c01 = __builtin_bit_cast(half2v, cv.x);
    half2v c23 = __builtin_bit_cast(half2v, cv.y);
    _Float16 a00 = c01[0], a01 = c01[1], a10 = c23[0], a11 = c23[1];
    half8 a00s = {a00, a00, a00, a00, a00, a00, a00, a00};
    half8 a01s = {a01, a01, a01, a01, a01, a01, a01, a01};
    half8 a10s = {a10, a10, a10, a10, a10, a10, a10, a10};
    half8 a11s = {a11, a11, a11, a11, a11, a11, a11, a11};
#pragma unroll
    for (int ch = 0; ch < 2; ++ch) {
      const int csl = ch * 4 + lq;
      half8 v00 = *(const half8*)(xs4 + rc00 * 9 + csl);
      half8 v01 = *(const half8*)(xs4 + rc01 * 9 + csl);
      half8 v10 = *(const half8*)(xs4 + rc10 * 9 + csl);
      half8 v11 = *(const half8*)(xs4 + rc11 * 9 + csl);
      half8 t = v00 * a00s + v01 * a01s + v10 * a10s + v11 * a11s;
      const int sidx = kk * 2 + ch;
#pragma unroll
      for (int ot = 0; ot < 4; ++ot) {
        half8 bw = wf8[(sidx * 4 + ot) * 64 + lane];
        acc[ot] = __builtin_amdgcn_mfma_f32_16x16x32_f16(bw, t, acc[ot], 0, 0, 0);
      }
    }
  }

  // ---- Epilogue: ReLU -> fp32 -> global ----
  const int h = r0 + wv;
  const int w = c0 + pcl;
#pragma unroll
  for (int ot = 0; ot < 4; ++ot) {
#pragma unroll
    for (int r = 0; r < 4; ++r) {
      int o = ot * 16 + lq * 4 + r;
      float v = fmaxf(acc[ot][r], 0.0f);
      out[((b * O_ + o) << 14) + (h << 7) + w] = v;
    }
  }
}

extern "C" void kernel_launch(void* const* d_in, const int* in_sizes, int n_in,
                              void* d_out, int out_size, void* d_ws, size_t ws_size,
                              hipStream_t stream) {
  const float* x   = (const float*)d_in[0];
  const float* ele = (const float*)d_in[1];
  const float* ow  = (const float*)d_in[2];
  const float* ob  = (const float*)d_in[3];
  const float* mw  = (const float*)d_in[4];
  const float* mb  = (const float*)d_in[5];
  const float* dw  = (const float*)d_in[6];
  _Float16* wsb = (_Float16*)d_ws;

  build_frags<<<180, 256, 0, stream>>>(dw, mw, wsb);
  deform_main<<<512, 512, 0, stream>>>(x, ele, ow, ob, mb, wsb,
                                       (float*)d_out);
}

// Round 14
// 31.222 us; speedup vs baseline: 4.2613x; 1.0304x over previous
//
#include <hip/hip_runtime.h>
#include <hip/hip_bf16.h>
#include <hip/hip_fp16.h>

typedef _Float16 half8 __attribute__((ext_vector_type(8)));
typedef _Float16 half2v __attribute__((ext_vector_type(2)));
typedef float f32x4 __attribute__((ext_vector_type(4)));

#define B_ 4
#define C_ 64
#define O_ 64
#define H_ 128
#define W_ 128
#define HT 8     // tile rows
#define WT 16    // tile cols
#define HALO 3
#define RS 14    // staged rows (HT + 2*HALO)
#define CS 22    // staged cols (WT + 2*HALO)
// xs layout: [pixel][ch], pixel stride 72 f16 = 144B = 9 half8/uint4 slots

__device__ __forceinline__ unsigned pkh(float lo, float hi) {
  half2v v = {(_Float16)lo, (_Float16)hi};
  return __builtin_bit_cast(unsigned, v);
}

// ---------------------------------------------------------------------------
// Kernel 0: pre-build fragment-ready f16 weights in workspace.
//  wf  (deform_w): 18 k-steps x 4 o-tiles x 64 lanes x 8 = 36864 f16
//  wfm (mask_w padded to 16 rows): 18 k-steps x 64 lanes x 8 = 9216 f16
// ---------------------------------------------------------------------------
__global__ void build_frags(const float* __restrict__ dw,
                            const float* __restrict__ mw,
                            _Float16* __restrict__ wsb) {
  int t = blockIdx.x * 256 + threadIdx.x;
  if (t < 36864) {
    int j = t & 7, lane = (t >> 3) & 63, ot = (t >> 9) & 3, s = t >> 11;
    int kk = s >> 1, ch = s & 1;
    int o = ot * 16 + (lane & 15);
    int c = ch * 32 + ((lane >> 4) << 3) + j;
    wsb[t] = (_Float16)dw[(o * 64 + c) * 9 + kk];
  } else if (t < 46080) {
    int t2 = t - 36864;
    int j = t2 & 7, lane = (t2 >> 3) & 63, s = t2 >> 9;
    int km = lane & 15;
    int c = (s & 1) * 32 + ((lane >> 4) << 3) + j;
    int tap = s >> 1;
    float v = (km < 9) ? mw[(km * 64 + c) * 9 + tap] : 0.0f;
    wsb[t] = (_Float16)v;
  }
}

// ---------------------------------------------------------------------------
// Main fused kernel. 512 blocks x 512 threads (8 waves).
// Phase 3: wave = pixel row (unchanged).
// Phase 4: SPLIT-K — wave wv handles px-group (wv&3)*32..+31 (2 fragments)
//          and sidx-half (wv>>2)*9..+8.  kh=1 partials reduced via LDS in
//          TWO passes (16384 B each <= 18432 B dynbuf).
// LDS: 44352 (xs) + 18432 (dynbuf: offl/cwb/crc, reused as redbuf) = 62784 B
// ---------------------------------------------------------------------------
__global__ __launch_bounds__(512, 4)
void deform_main(const float* __restrict__ x,
                 const float* __restrict__ ele,
                 const float* __restrict__ ow,
                 const float* __restrict__ ob,
                 const float* __restrict__ mb,
                 const _Float16* __restrict__ wsb,
                 float* __restrict__ out) {
  __shared__ uint4 xs4[RS * CS * 9];       // 44352 B, f16 data
  __shared__ uint4 dynbuf4[1152];          // 18432 B multi-use
  _Float16* offl = (_Float16*)dynbuf4;                       // 4608 B
  uint2* cwb = (uint2*)((char*)dynbuf4 + 4608);              // 9216 B
  unsigned* crc = (unsigned*)((char*)dynbuf4 + 4608 + 9216); // 4608 B
  f32x4* redbuf = (f32x4*)dynbuf4;         // 16384 B per pass, after phase 4

  const int tid = threadIdx.x;
  const int lane = tid & 63;
  const int wv = tid >> 6;        // 0..7
  const int pcl = lane & 15;      // MFMA col
  const int lq = lane >> 4;       // k-slice quadrant

  // XCD-bijective swizzle: consecutive decoded tiles land on the same XCD.
  const int bid = blockIdx.x;
  const int d = ((bid & 7) << 6) + (bid >> 3);   // 512 % 8 == 0 -> bijective
  const int b = d >> 7;
  const int t7 = d & 127;
  const int r0 = (t7 >> 3) * HT;   // 16 row-tiles
  const int c0 = (t7 & 7) * WT;    // 8 col-tiles

  // ---- Early: issue phase-2 ele loads (latency hidden under staging) -----
  float ev[9];
  {
    int tl = tid & 127;
    int pr = tl >> 4, pc = tl & 15;
    int h = r0 + pr, w = c0 + pc;
#pragma unroll
    for (int ty = 0; ty < 3; ++ty)
#pragma unroll
      for (int tx = 0; tx < 3; ++tx) {
        int gy = h - 1 + ty, gx = w - 1 + tx;
        float v = 0.0f;
        if ((unsigned)gy < 128u && (unsigned)gx < 128u)
          v = ele[b * (H_ * W_) + (gy << 7) + gx];
        ev[ty * 3 + tx] = v;
      }
  }

  // ---- Phase 1: stage x patch to LDS as f16, packed-pair writes ----------
  {
    _Float16* xsb = (_Float16*)xs4;
    const int c2 = tid >> 4;               // 0..31
    const int pl = tid & 15;
    const float* xb0 = x + b * (C_ * H_ * W_) + (2 * c2) * (H_ * W_);
    const float* xb1 = xb0 + (H_ * W_);
    for (int p = pl; p < RS * CS; p += 16) {
      int row = (p * 2979) >> 16;          // p / 22 for p < 700
      int col = p - row * CS;
      int gy = r0 - HALO + row, gx = c0 - HALO + col;
      float v0 = 0.0f, v1 = 0.0f;
      if ((unsigned)gy < 128u && (unsigned)gx < 128u) {
        int gi = (gy << 7) + gx;
        v0 = xb0[gi];
        v1 = xb1[gi];
      }
      half2v hv = {(_Float16)v0, (_Float16)v1};
      *(half2v*)&xsb[p * 72 + 2 * c2] = hv;
    }
  }

  // ---- Phase 2: offset conv (1->18ch 3x3), threads < 128, one px each ----
  if (tid < 128) {
#pragma unroll
    for (int ci = 0; ci < 18; ++ci) {
      float a = ob[ci];
#pragma unroll
      for (int tap = 0; tap < 9; ++tap) a += ev[tap] * ow[ci * 9 + tap];
      offl[tid * 18 + ci] = (_Float16)a;
    }
  }
  __syncthreads();   // xs + offl ready

  // ---- Phase 3: mask conv via f16 MFMA + FUSED sigmoid+coef epilogue -----
  {
    const half8* wfm8 = ((const half8*)wsb) + 4608;  // after 36864 f16
    f32x4 macc = {0.f, 0.f, 0.f, 0.f};
#pragma unroll
    for (int s = 0; s < 18; ++s) {
      const int tap = s >> 1;
      const int chalf = s & 1;
      const int ty = tap / 3, tx = tap - ty * 3;
      half8 aw = wfm8[s * 64 + lane];
      const int csl = chalf * 4 + lq;
      int rc = (wv + (HALO - 1) + ty) * CS + (pcl + (HALO - 1) + tx);
      half8 xv = *(const half8*)(xs4 + rc * 9 + csl);
      macc = __builtin_amdgcn_mfma_f32_16x16x32_f16(aw, xv, macc, 0, 0, 0);
    }
    // Fused epilogue: this lane owns (px, kk = lq*4 + r), exact cover of 0..8.
    const int px = wv * 16 + pcl;
    const int h = r0 + wv, w = c0 + pcl;
#pragma unroll
    for (int r = 0; r < 4; ++r) {
      int kk = lq * 4 + r;
      if (kk < 9) {
        float a = macc[r] + mb[kk];
        float m = 1.0f / (1.0f + __expf(-a));
        int ky = kk / 3 - 1;
        int kx = kk - (kk / 3) * 3 - 1;
        half2v o2 = *(const half2v*)&offl[px * 18 + kk * 2];
        float py = (float)(h + ky) + (float)o2[0];
        float pxx = (float)(w + kx) + (float)o2[1];
        float fy = floorf(py), fx = floorf(pxx);
        float wy = py - fy, wx = pxx - fx;
        int iy = (int)fy - r0 + HALO;
        int ix = (int)fx - c0 + HALO;
        int vy0 = (unsigned)iy < (unsigned)RS;
        int vy1 = (unsigned)(iy + 1) < (unsigned)RS;
        int vx0 = (unsigned)ix < (unsigned)CS;
        int vx1 = (unsigned)(ix + 1) < (unsigned)CS;
        int cy0 = min(max(iy, 0), RS - 1), cy1 = min(max(iy + 1, 0), RS - 1);
        int cx0 = min(max(ix, 0), CS - 1), cx1 = min(max(ix + 1, 0), CS - 1);
        float wy0 = 1.0f - wy, wx0 = 1.0f - wx;
        float a00 = wy0 * wx0 * m * (float)(vy0 & vx0);
        float a01 = wy0 * wx * m * (float)(vy0 & vx1);
        float a10 = wy * wx0 * m * (float)(vy1 & vx0);
        float a11 = wy * wx * m * (float)(vy1 & vx1);
        int rc00 = cy0 * CS + cx0;
        int drow = (cy1 - cy0) * CS;           // 0 or 22
        int dcol = cx1 - cx0;                  // 0 or 1
        uint2 cv;
        cv.x = pkh(a00, a01);
        cv.y = pkh(a10, a11);
        cwb[px * 9 + kk] = cv;
        crc[px * 9 + kk] =
            (unsigned)rc00 | ((unsigned)drow << 16) | ((unsigned)dcol << 24);
      }
    }
  }
  __syncthreads();   // coefficients ready

  // ---- Phase 4: split-K gather-blend + MFMA ------------------------------
  const half8* wf8 = (const half8*)wsb;
  const int pxg = wv & 3;        // pixel group: 32 px
  const int kh = wv >> 2;        // sidx half: 0 -> 0..8, 1 -> 9..17
  f32x4 acc[2][4];
#pragma unroll
  for (int pt = 0; pt < 2; ++pt)
#pragma unroll
    for (int ot = 0; ot < 4; ++ot) {
      f32x4 z = {0.f, 0.f, 0.f, 0.f};
      acc[pt][ot] = z;
    }

  const int pxA = pxg * 32 + pcl;        // pt = 0
  const int pxB = pxA + 16;              // pt = 1

#pragma unroll
  for (int s = 0; s < 9; ++s) {
    const int sidx = kh * 9 + s;
    const int kk = sidx >> 1;
    const int ch = sidx & 1;
    const int csl = ch * 4 + lq;
    half8 t[2];
#pragma unroll
    for (int pt = 0; pt < 2; ++pt) {
      const int px = pt ? pxB : pxA;
      uint2 cv = cwb[px * 9 + kk];
      unsigned rv = crc[px * 9 + kk];
      int rc00 = rv & 0xFFFF;
      int drow = (rv >> 16) & 0xFF;
      int dcol = rv >> 24;
      int rc01 = rc00 + dcol;
      int rc10 = rc00 + drow;
      int rc11 = rc10 + dcol;
      half2v c01 = __builtin_bit_cast(half2v, cv.x);
      half2v c23 = __builtin_bit_cast(half2v, cv.y);
      _Float16 a00 = c01[0], a01 = c01[1], a10 = c23[0], a11 = c23[1];
      half8 a00s = {a00, a00, a00, a00, a00, a00, a00, a00};
      half8 a01s = {a01, a01, a01, a01, a01, a01, a01, a01};
      half8 a10s = {a10, a10, a10, a10, a10, a10, a10, a10};
      half8 a11s = {a11, a11, a11, a11, a11, a11, a11, a11};
      half8 v00 = *(const half8*)(xs4 + rc00 * 9 + csl);
      half8 v01 = *(const half8*)(xs4 + rc01 * 9 + csl);
      half8 v10 = *(const half8*)(xs4 + rc10 * 9 + csl);
      half8 v11 = *(const half8*)(xs4 + rc11 * 9 + csl);
      t[pt] = v00 * a00s + v01 * a01s + v10 * a10s + v11 * a11s;
    }
#pragma unroll
    for (int ot = 0; ot < 4; ++ot) {
      half8 bw = wf8[(sidx * 4 + ot) * 64 + lane];
      acc[0][ot] = __builtin_amdgcn_mfma_f32_16x16x32_f16(bw, t[0], acc[0][ot], 0, 0, 0);
      acc[1][ot] = __builtin_amdgcn_mfma_f32_16x16x32_f16(bw, t[1], acc[1][ot], 0, 0, 0);
    }
  }

  __syncthreads();   // all waves done reading cwb/crc; dynbuf reusable

  // ---- Two-pass reduction + epilogue (16384 B redbuf per pass) -----------
#pragma unroll
  for (int pt = 0; pt < 2; ++pt) {
    if (kh == 1) {
#pragma unroll
      for (int ot = 0; ot < 4; ++ot)
        redbuf[((pxg * 4 + ot) * 4 + lq) * 16 + pcl] = acc[pt][ot];
    }
    __syncthreads();
    if (kh == 0) {
      const int px = pt ? pxB : pxA;
      const int h = r0 + (px >> 4);
      const int w = c0 + pcl;
#pragma unroll
      for (int ot = 0; ot < 4; ++ot) {
        f32x4 other = redbuf[((pxg * 4 + ot) * 4 + lq) * 16 + pcl];
#pragma unroll
        for (int r = 0; r < 4; ++r) {
          int o = ot * 16 + lq * 4 + r;
          float v = fmaxf(acc[pt][ot][r] + other[r], 0.0f);
          out[((b * O_ + o) << 14) + (h << 7) + w] = v;
        }
      }
    }
    __syncthreads();
  }
}

extern "C" void kernel_launch(void* const* d_in, const int* in_sizes, int n_in,
                              void* d_out, int out_size, void* d_ws, size_t ws_size,
                              hipStream_t stream) {
  const float* x   = (const float*)d_in[0];
  const float* ele = (const float*)d_in[1];
  const float* ow  = (const float*)d_in[2];
  const float* ob  = (const float*)d_in[3];
  const float* mw  = (const float*)d_in[4];
  const float* mb  = (const float*)d_in[5];
  const float* dw  = (const float*)d_in[6];
  _Float16* wsb = (_Float16*)d_ws;

  build_frags<<<180, 256, 0, stream>>>(dw, mw, wsb);
  deform_main<<<512, 512, 0, stream>>>(x, ele, ow, ob, mb, wsb,
                                       (float*)d_out);
}

// Round 15
// 30.555 us; speedup vs baseline: 4.3543x; 1.0218x over previous
//
#include <hip/hip_runtime.h>
#include <hip/hip_bf16.h>
#include <hip/hip_fp16.h>

typedef _Float16 half8 __attribute__((ext_vector_type(8)));
typedef _Float16 half2v __attribute__((ext_vector_type(2)));
typedef float f32x4 __attribute__((ext_vector_type(4)));

#define B_ 4
#define C_ 64
#define O_ 64
#define H_ 128
#define W_ 128
#define HT 8     // tile rows
#define WT 16    // tile cols
#define HALO 3
#define RS 14    // staged rows (HT + 2*HALO)
#define CS 22    // staged cols (WT + 2*HALO)
// xs layout: [pixel][ch], pixel stride 72 f16 = 144B = 9 half8/uint4 slots

__device__ __forceinline__ unsigned pkh(float lo, float hi) {
  half2v v = {(_Float16)lo, (_Float16)hi};
  return __builtin_bit_cast(unsigned, v);
}

// ---------------------------------------------------------------------------
// Kernel 0: pre-build fragment-ready f16 weights in workspace.
//  wf  (deform_w): 18 k-steps x 4 o-tiles x 64 lanes x 8 = 36864 f16
//  wfm (mask_w padded to 16 rows): 18 k-steps x 64 lanes x 8 = 9216 f16
// ---------------------------------------------------------------------------
__global__ void build_frags(const float* __restrict__ dw,
                            const float* __restrict__ mw,
                            _Float16* __restrict__ wsb) {
  int t = blockIdx.x * 256 + threadIdx.x;
  if (t < 36864) {
    int j = t & 7, lane = (t >> 3) & 63, ot = (t >> 9) & 3, s = t >> 11;
    int kk = s >> 1, ch = s & 1;
    int o = ot * 16 + (lane & 15);
    int c = ch * 32 + ((lane >> 4) << 3) + j;
    wsb[t] = (_Float16)dw[(o * 64 + c) * 9 + kk];
  } else if (t < 46080) {
    int t2 = t - 36864;
    int j = t2 & 7, lane = (t2 >> 3) & 63, s = t2 >> 9;
    int km = lane & 15;
    int c = (s & 1) * 32 + ((lane >> 4) << 3) + j;
    int tap = s >> 1;
    float v = (km < 9) ? mw[(km * 64 + c) * 9 + tap] : 0.0f;
    wsb[t] = (_Float16)v;
  }
}

// ---------------------------------------------------------------------------
// Main fused kernel. 512 blocks x 512 threads (8 waves).
// Phase 1: vectorized staging on even-aligned float2 column pairs.
// Phase 3: wave = pixel row; fused sigmoid+coef epilogue.
// Phase 4: SPLIT-K (wave = px-group x sidx-half); two-pass LDS reduction.
// LDS: 44352 (xs) + 18432 (dynbuf: offl/cwb/crc, reused as redbuf) = 62784 B
// ---------------------------------------------------------------------------
__global__ __launch_bounds__(512, 4)
void deform_main(const float* __restrict__ x,
                 const float* __restrict__ ele,
                 const float* __restrict__ ow,
                 const float* __restrict__ ob,
                 const float* __restrict__ mb,
                 const _Float16* __restrict__ wsb,
                 float* __restrict__ out) {
  __shared__ uint4 xs4[RS * CS * 9];       // 44352 B, f16 data
  __shared__ uint4 dynbuf4[1152];          // 18432 B multi-use
  _Float16* offl = (_Float16*)dynbuf4;                       // 4608 B
  uint2* cwb = (uint2*)((char*)dynbuf4 + 4608);              // 9216 B
  unsigned* crc = (unsigned*)((char*)dynbuf4 + 4608 + 9216); // 4608 B
  f32x4* redbuf = (f32x4*)dynbuf4;         // 16384 B per pass, after phase 4

  const int tid = threadIdx.x;
  const int lane = tid & 63;
  const int wv = tid >> 6;        // 0..7
  const int pcl = lane & 15;      // MFMA col
  const int lq = lane >> 4;       // k-slice quadrant

  // XCD-bijective swizzle: consecutive decoded tiles land on the same XCD.
  const int bid = blockIdx.x;
  const int d = ((bid & 7) << 6) + (bid >> 3);   // 512 % 8 == 0 -> bijective
  const int b = d >> 7;
  const int t7 = d & 127;
  const int r0 = (t7 >> 3) * HT;   // 16 row-tiles
  const int c0 = (t7 & 7) * WT;    // 8 col-tiles

  // ---- Early: issue phase-2 ele loads (latency hidden under staging) -----
  float ev[9];
  {
    int tl = tid & 127;
    int pr = tl >> 4, pc = tl & 15;
    int h = r0 + pr, w = c0 + pc;
#pragma unroll
    for (int ty = 0; ty < 3; ++ty)
#pragma unroll
      for (int tx = 0; tx < 3; ++tx) {
        int gy = h - 1 + ty, gx = w - 1 + tx;
        float v = 0.0f;
        if ((unsigned)gy < 128u && (unsigned)gx < 128u)
          v = ele[b * (H_ * W_) + (gy << 7) + gx];
        ev[ty * 3 + tx] = v;
      }
  }

  // ---- Phase 1: stage x patch to LDS as f16 -------------------------------
  // Even-aligned float2 column pairs: item it = (row, pc2); pair covers
  // gx = c0-4+2*pc2, gx+1 (always even -> 8B-aligned float2; fully in or
  // fully out of [0,127], no partial case). 12 pairs x 14 rows = 168 items.
  // Pair-grid edges: col 2*pc2-1 == -1 (pc2=0) and 2*pc2 == 22 (pc2=11)
  // are skipped on write.
  {
    _Float16* xsb = (_Float16*)xs4;
    const int c2 = tid >> 4;               // 0..31 channel pair
    const int pl = tid & 15;
    const float* xb0 = x + b * (C_ * H_ * W_) + (2 * c2) * (H_ * W_);
    const float* xb1 = xb0 + (H_ * W_);
    for (int it = pl; it < 168; it += 16) {
      int row = (it * 5462) >> 16;         // it / 12 for it < 168
      int pc2 = it - row * 12;
      int gy = r0 - HALO + row;
      int gx = c0 - 4 + 2 * pc2;           // even
      float2 a = {0.0f, 0.0f}, bv = {0.0f, 0.0f};
      if ((unsigned)gy < 128u && (unsigned)gx < 127u) {
        int gi = (gy << 7) + gx;
        a = *(const float2*)(xb0 + gi);
        bv = *(const float2*)(xb1 + gi);
      }
      int cp = 2 * pc2 - 1;                // patch col of first px in pair
      int p = row * CS + cp;
      if (pc2 > 0) {
        half2v h0 = {(_Float16)a.x, (_Float16)bv.x};
        *(half2v*)(xsb + p * 72 + 2 * c2) = h0;
      }
      if (pc2 < 11) {
        half2v h1 = {(_Float16)a.y, (_Float16)bv.y};
        *(half2v*)(xsb + (p + 1) * 72 + 2 * c2) = h1;
      }
    }
  }

  // ---- Phase 2: offset conv (1->18ch 3x3), threads < 128, one px each ----
  if (tid < 128) {
#pragma unroll
    for (int ci = 0; ci < 18; ++ci) {
      float a = ob[ci];
#pragma unroll
      for (int tap = 0; tap < 9; ++tap) a += ev[tap] * ow[ci * 9 + tap];
      offl[tid * 18 + ci] = (_Float16)a;
    }
  }
  __syncthreads();   // xs + offl ready

  // ---- Phase 3: mask conv via f16 MFMA + FUSED sigmoid+coef epilogue -----
  {
    const half8* wfm8 = ((const half8*)wsb) + 4608;  // after 36864 f16
    f32x4 macc = {0.f, 0.f, 0.f, 0.f};
#pragma unroll
    for (int s = 0; s < 18; ++s) {
      const int tap = s >> 1;
      const int chalf = s & 1;
      const int ty = tap / 3, tx = tap - ty * 3;
      half8 aw = wfm8[s * 64 + lane];
      const int csl = chalf * 4 + lq;
      int rc = (wv + (HALO - 1) + ty) * CS + (pcl + (HALO - 1) + tx);
      half8 xv = *(const half8*)(xs4 + rc * 9 + csl);
      macc = __builtin_amdgcn_mfma_f32_16x16x32_f16(aw, xv, macc, 0, 0, 0);
    }
    // Fused epilogue: this lane owns (px, kk = lq*4 + r), exact cover of 0..8.
    const int px = wv * 16 + pcl;
    const int h = r0 + wv, w = c0 + pcl;
#pragma unroll
    for (int r = 0; r < 4; ++r) {
      int kk = lq * 4 + r;
      if (kk < 9) {
        float a = macc[r] + mb[kk];
        float m = 1.0f / (1.0f + __expf(-a));
        int ky = kk / 3 - 1;
        int kx = kk - (kk / 3) * 3 - 1;
        half2v o2 = *(const half2v*)&offl[px * 18 + kk * 2];
        float py = (float)(h + ky) + (float)o2[0];
        float pxx = (float)(w + kx) + (float)o2[1];
        float fy = floorf(py), fx = floorf(pxx);
        float wy = py - fy, wx = pxx - fx;
        int iy = (int)fy - r0 + HALO;
        int ix = (int)fx - c0 + HALO;
        int vy0 = (unsigned)iy < (unsigned)RS;
        int vy1 = (unsigned)(iy + 1) < (unsigned)RS;
        int vx0 = (unsigned)ix < (unsigned)CS;
        int vx1 = (unsigned)(ix + 1) < (unsigned)CS;
        int cy0 = min(max(iy, 0), RS - 1), cy1 = min(max(iy + 1, 0), RS - 1);
        int cx0 = min(max(ix, 0), CS - 1), cx1 = min(max(ix + 1, 0), CS - 1);
        float wy0 = 1.0f - wy, wx0 = 1.0f - wx;
        float a00 = wy0 * wx0 * m * (float)(vy0 & vx0);
        float a01 = wy0 * wx * m * (float)(vy0 & vx1);
        float a10 = wy * wx0 * m * (float)(vy1 & vx0);
        float a11 = wy * wx * m * (float)(vy1 & vx1);
        int rc00 = cy0 * CS + cx0;
        int drow = (cy1 - cy0) * CS;           // 0 or 22
        int dcol = cx1 - cx0;                  // 0 or 1
        uint2 cv;
        cv.x = pkh(a00, a01);
        cv.y = pkh(a10, a11);
        cwb[px * 9 + kk] = cv;
        crc[px * 9 + kk] =
            (unsigned)rc00 | ((unsigned)drow << 16) | ((unsigned)dcol << 24);
      }
    }
  }
  __syncthreads();   // coefficients ready

  // ---- Phase 4: split-K gather-blend + MFMA ------------------------------
  const half8* wf8 = (const half8*)wsb;
  const int pxg = wv & 3;        // pixel group: 32 px
  const int kh = wv >> 2;        // sidx half: 0 -> 0..8, 1 -> 9..17
  f32x4 acc[2][4];
#pragma unroll
  for (int pt = 0; pt < 2; ++pt)
#pragma unroll
    for (int ot = 0; ot < 4; ++ot) {
      f32x4 z = {0.f, 0.f, 0.f, 0.f};
      acc[pt][ot] = z;
    }

  const int pxA = pxg * 32 + pcl;        // pt = 0
  const int pxB = pxA + 16;              // pt = 1

#pragma unroll
  for (int s = 0; s < 9; ++s) {
    const int sidx = kh * 9 + s;
    const int kk = sidx >> 1;
    const int ch = sidx & 1;
    const int csl = ch * 4 + lq;
    half8 t[2];
#pragma unroll
    for (int pt = 0; pt < 2; ++pt) {
      const int px = pt ? pxB : pxA;
      uint2 cv = cwb[px * 9 + kk];
      unsigned rv = crc[px * 9 + kk];
      int rc00 = rv & 0xFFFF;
      int drow = (rv >> 16) & 0xFF;
      int dcol = rv >> 24;
      int rc01 = rc00 + dcol;
      int rc10 = rc00 + drow;
      int rc11 = rc10 + dcol;
      half2v c01 = __builtin_bit_cast(half2v, cv.x);
      half2v c23 = __builtin_bit_cast(half2v, cv.y);
      _Float16 a00 = c01[0], a01 = c01[1], a10 = c23[0], a11 = c23[1];
      half8 a00s = {a00, a00, a00, a00, a00, a00, a00, a00};
      half8 a01s = {a01, a01, a01, a01, a01, a01, a01, a01};
      half8 a10s = {a10, a10, a10, a10, a10, a10, a10, a10};
      half8 a11s = {a11, a11, a11, a11, a11, a11, a11, a11};
      half8 v00 = *(const half8*)(xs4 + rc00 * 9 + csl);
      half8 v01 = *(const half8*)(xs4 + rc01 * 9 + csl);
      half8 v10 = *(const half8*)(xs4 + rc10 * 9 + csl);
      half8 v11 = *(const half8*)(xs4 + rc11 * 9 + csl);
      t[pt] = v00 * a00s + v01 * a01s + v10 * a10s + v11 * a11s;
    }
#pragma unroll
    for (int ot = 0; ot < 4; ++ot) {
      half8 bw = wf8[(sidx * 4 + ot) * 64 + lane];
      acc[0][ot] = __builtin_amdgcn_mfma_f32_16x16x32_f16(bw, t[0], acc[0][ot], 0, 0, 0);
      acc[1][ot] = __builtin_amdgcn_mfma_f32_16x16x32_f16(bw, t[1], acc[1][ot], 0, 0, 0);
    }
  }

  __syncthreads();   // all waves done reading cwb/crc; dynbuf reusable

  // ---- Two-pass reduction + epilogue (16384 B redbuf per pass) -----------
#pragma unroll
  for (int pt = 0; pt < 2; ++pt) {
    if (kh == 1) {
#pragma unroll
      for (int ot = 0; ot < 4; ++ot)
        redbuf[((pxg * 4 + ot) * 4 + lq) * 16 + pcl] = acc[pt][ot];
    }
    __syncthreads();
    if (kh == 0) {
      const int px = pt ? pxB : pxA;
      const int h = r0 + (px >> 4);
      const int w = c0 + pcl;
#pragma unroll
      for (int ot = 0; ot < 4; ++ot) {
        f32x4 other = redbuf[((pxg * 4 + ot) * 4 + lq) * 16 + pcl];
#pragma unroll
        for (int r = 0; r < 4; ++r) {
          int o = ot * 16 + lq * 4 + r;
          float v = fmaxf(acc[pt][ot][r] + other[r], 0.0f);
          out[((b * O_ + o) << 14) + (h << 7) + w] = v;
        }
      }
    }
    __syncthreads();
  }
}

extern "C" void kernel_launch(void* const* d_in, const int* in_sizes, int n_in,
                              void* d_out, int out_size, void* d_ws, size_t ws_size,
                              hipStream_t stream) {
  const float* x   = (const float*)d_in[0];
  const float* ele = (const float*)d_in[1];
  const float* ow  = (const float*)d_in[2];
  const float* ob  = (const float*)d_in[3];
  const float* mw  = (const float*)d_in[4];
  const float* mb  = (const float*)d_in[5];
  const float* dw  = (const float*)d_in[6];
  _Float16* wsb = (_Float16*)d_ws;

  build_frags<<<180, 256, 0, stream>>>(dw, mw, wsb);
  deform_main<<<512, 512, 0, stream>>>(x, ele, ow, ob, mb, wsb,
                                       (float*)d_out);
}